// Round 3
// baseline (774.796 us; speedup 1.0000x reference)
//
#include <hip/hip_runtime.h>
#include <stdint.h>

// ThorMoE: per-expert 2-layer MLP.
// E=16, T=512, H=1024, I=4096. fp32 in/out, f16 MFMA compute internally
// (threshold is 2% of max|ref| -> f16+fp32-accum error ~0.2%, safe).
// Kernel 1: h[e,t,i] = x[e,t,:] @ W1[e,:,i] + b1[e,i]   (M=512,N=4096,K=1024), h in ws as f16
// Kernel 2: y[e,t,h] = h[e,t,:] @ W2[e,:,h] + b2[e,h]   (M=512,N=1024,K=4096), y fp32 to d_out
// 128x128 tile, BK=32, 256 threads = 4 waves (2x2), 4x4 16x16x32 MFMA frags/wave.
// B (weights) are N-contiguous -> transposed into LDS [n][k] during staging.

#define E_ 16
#define T_ 512
#define H_ 1024
#define I_ 4096

typedef _Float16 f16x8 __attribute__((ext_vector_type(8)));
typedef __fp16   h2    __attribute__((ext_vector_type(2)));  // cvt_pkrtz result type
typedef float    f32x4 __attribute__((ext_vector_type(4)));

#define LDK 40  // LDS row stride in f16 elems: 32 + 8 pad (keeps 16B align for b128, breaks pow2 banks)

template <bool A_IS_F16, bool OUT_IS_F16>
__global__ __launch_bounds__(256, 2) void moe_gemm(const void* __restrict__ Aall,
                                                   const float* __restrict__ Ball,
                                                   const float* __restrict__ biasAll,
                                                   void* __restrict__ Call,
                                                   int M, int N, int K) {
    __shared__ _Float16 sA[128 * LDK];
    __shared__ _Float16 sB[128 * LDK];

    const int e   = blockIdx.z;
    const int m0  = blockIdx.y * 128;
    const int n0  = blockIdx.x * 128;
    const int tid = threadIdx.x;
    const int lane = tid & 63;
    const int wave = tid >> 6;
    const int wm = (wave >> 1) * 64;   // wave row offset in tile
    const int wn = (wave & 1) * 64;    // wave col offset in tile
    const int lrow = lane & 15;        // m (or n) within 16x16 frag
    const int lk8  = (lane >> 4) * 8;  // k offset within frag

    const float* B_e    = Ball + (size_t)e * K * N;
    const float* bias_e = biasAll + (size_t)e * N;
    const float*     A_f32 = (const float*)Aall + (size_t)e * M * K;
    const _Float16*  A_f16 = (const _Float16*)Aall + (size_t)e * M * K;

    f32x4 acc[4][4];
    const f32x4 zero = {0.f, 0.f, 0.f, 0.f};
#pragma unroll
    for (int i = 0; i < 4; ++i)
#pragma unroll
        for (int j = 0; j < 4; ++j) acc[i][j] = zero;

    for (int k0 = 0; k0 < K; k0 += 32) {
        // ---- stage A tile: [128 rows m][32 k], k-contiguous in LDS ----
        if (A_IS_F16) {
            const int r  = tid >> 2;          // 0..63
            const int c8 = (tid & 3) * 8;     // 0,8,16,24
#pragma unroll
            for (int p = 0; p < 2; ++p) {
                const int row = r + p * 64;
                f16x8 v = *(const f16x8*)(A_f16 + (size_t)(m0 + row) * K + k0 + c8);
                *(f16x8*)&sA[row * LDK + c8] = v;
            }
        } else {
            const int r  = tid >> 3;          // 0..31
            const int c4 = (tid & 7) * 4;     // 0,4,...,28
#pragma unroll
            for (int p = 0; p < 4; ++p) {
                const int row = r + p * 32;
                f32x4 v = *(const f32x4*)(A_f32 + (size_t)(m0 + row) * K + k0 + c4);
                h2 lo = __builtin_amdgcn_cvt_pkrtz(v.x, v.y);
                h2 hi = __builtin_amdgcn_cvt_pkrtz(v.z, v.w);
                *(h2*)&sA[row * LDK + c4]     = lo;
                *(h2*)&sA[row * LDK + c4 + 2] = hi;
            }
        }
        // ---- stage B tile with transpose: global [k][n] -> LDS [n][k] ----
        {
            const int nb = (tid & 31) * 4;    // 0..124
            const int kp = (tid >> 5) * 2;    // 0,2,...,14
#pragma unroll
            for (int p = 0; p < 2; ++p) {
                const int k = kp + p * 16;
                const float* src = B_e + (size_t)(k0 + k) * N + n0 + nb;
                f32x4 va = *(const f32x4*)src;        // row k,   n..n+3
                f32x4 vb = *(const f32x4*)(src + N);  // row k+1, n..n+3
                *(h2*)&sB[(nb + 0) * LDK + k] = __builtin_amdgcn_cvt_pkrtz(va.x, vb.x);
                *(h2*)&sB[(nb + 1) * LDK + k] = __builtin_amdgcn_cvt_pkrtz(va.y, vb.y);
                *(h2*)&sB[(nb + 2) * LDK + k] = __builtin_amdgcn_cvt_pkrtz(va.z, vb.z);
                *(h2*)&sB[(nb + 3) * LDK + k] = __builtin_amdgcn_cvt_pkrtz(va.w, vb.w);
            }
        }
        __syncthreads();

        // ---- fragments + MFMA ----
        f16x8 af[4], bf[4];
#pragma unroll
        for (int mi = 0; mi < 4; ++mi)
            af[mi] = *(const f16x8*)&sA[(wm + mi * 16 + lrow) * LDK + lk8];
#pragma unroll
        for (int ni = 0; ni < 4; ++ni)
            bf[ni] = *(const f16x8*)&sB[(wn + ni * 16 + lrow) * LDK + lk8];
#pragma unroll
        for (int mi = 0; mi < 4; ++mi)
#pragma unroll
            for (int ni = 0; ni < 4; ++ni)
                acc[mi][ni] = __builtin_amdgcn_mfma_f32_16x16x32_f16(af[mi], bf[ni], acc[mi][ni], 0, 0, 0);
        __syncthreads();
    }

    // ---- epilogue: C/D layout col=lane&15, row=(lane>>4)*4+reg (verified m89/m91) ----
    const int row_base = (lane >> 4) * 4;
#pragma unroll
    for (int ni = 0; ni < 4; ++ni) {
        const int n = n0 + wn + ni * 16 + lrow;
        const float bv = bias_e[n];
#pragma unroll
        for (int mi = 0; mi < 4; ++mi) {
            const int mbase = m0 + wm + mi * 16 + row_base;
#pragma unroll
            for (int r = 0; r < 4; ++r) {
                const float val = acc[mi][ni][r] + bv;
                const size_t idx = (size_t)e * M * N + (size_t)(mbase + r) * N + n;
                if (OUT_IS_F16)
                    ((_Float16*)Call)[idx] = (_Float16)val;
                else
                    ((float*)Call)[idx] = val;
            }
        }
    }
}

extern "C" void kernel_launch(void* const* d_in, const int* in_sizes, int n_in,
                              void* d_out, int out_size, void* d_ws, size_t ws_size,
                              hipStream_t stream) {
    (void)in_sizes; (void)n_in; (void)out_size; (void)ws_size;
    const float* x  = (const float*)d_in[0];  // (E,T,H)
    const float* W1 = (const float*)d_in[1];  // (E,H,I)
    const float* b1 = (const float*)d_in[2];  // (E,I)
    const float* W2 = (const float*)d_in[3];  // (E,I,H)
    const float* b2 = (const float*)d_in[4];  // (E,H)
    float* out = (float*)d_out;               // (E*T, H) fp32
    _Float16* hbuf = (_Float16*)d_ws;         // (E,T,I) f16 intermediate, 67.1 MB

    dim3 blk(256, 1, 1);
    dim3 g1(I_ / 128, T_ / 128, E_);  // 32 x 4 x 16 = 2048 blocks
    moe_gemm<false, true><<<g1, blk, 0, stream>>>((const void*)x, W1, b1, (void*)hbuf, T_, I_, H_);
    dim3 g2(H_ / 128, T_ / 128, E_);  // 8 x 4 x 16 = 512 blocks
    moe_gemm<true, false><<<g2, blk, 0, stream>>>((const void*)hbuf, W2, b2, (void*)out, T_, H_, I_);
}